// Round 1
// baseline (1680.159 us; speedup 1.0000x reference)
//
#include <hip/hip_runtime.h>

#define D_IN 128
#define D_HID 256
#define D_OUT 128
#define BN_EPS 1e-5f

// ---------------------------------------------------------------------------
// 1) SpMM scatter: agg[rows[e]] += vals[e] * v[cols[e]]   (fp32 atomics)
//    thread = (edge, 4-feature chunk); 32 threads per edge, float4 gather.
// ---------------------------------------------------------------------------
__global__ __launch_bounds__(256) void spmm_scatter(
    const float* __restrict__ v, const int* __restrict__ rows,
    const int* __restrict__ cols, const float* __restrict__ vals,
    float* __restrict__ agg, int E)
{
    int idx = blockIdx.x * 256 + threadIdx.x;
    int e = idx >> 5;
    if (e >= E) return;
    int c = (idx & 31) << 2;
    int r = rows[e];
    int cl = cols[e];
    float val = vals[e];
    const float4 vv = *reinterpret_cast<const float4*>(v + (size_t)cl * D_IN + c);
    float* dst = agg + (size_t)r * D_IN + c;
    atomicAdd(dst + 0, val * vv.x);
    atomicAdd(dst + 1, val * vv.y);
    atomicAdd(dst + 2, val * vv.z);
    atomicAdd(dst + 3, val * vv.w);
}

// ---------------------------------------------------------------------------
// 2) GEMM1: y1 = (agg + eps*v) @ w1      [M,128]x[128,256] -> [M,256]
//    64x64 tile, 256 threads, 4x4 microtile, BK=32, fp32 VALU.
// ---------------------------------------------------------------------------
__global__ __launch_bounds__(256) void gemm1(
    const float* __restrict__ agg, const float* __restrict__ v,
    const float* __restrict__ epsp, const float* __restrict__ w1,
    float* __restrict__ y1, int M)
{
    __shared__ __align__(16) float As[32][68];   // [k][m], padded
    __shared__ __align__(16) float Bs[32][64];   // [k][n]
    const int tid = threadIdx.x;
    const int bm = blockIdx.x * 64;
    const int bn = blockIdx.y * 64;
    const float eps = *epsp;
    const int lr = tid >> 3, lc = (tid & 7) << 2;   // A tile loader
    const int br = tid >> 4, bc = (tid & 15) << 2;  // B tile loader
    const int ty = tid >> 4, tx = tid & 15;         // compute layout
    float acc[4][4] = {};

    for (int kk = 0; kk < D_IN; kk += 32) {
#pragma unroll
        for (int h = 0; h < 2; ++h) {
            int row = bm + lr + h * 32;
            float4 a = make_float4(0.f, 0.f, 0.f, 0.f);
            if (row < M) {
                const float4 ag = *reinterpret_cast<const float4*>(agg + (size_t)row * D_IN + kk + lc);
                const float4 vv = *reinterpret_cast<const float4*>(v + (size_t)row * D_IN + kk + lc);
                a.x = fmaf(eps, vv.x, ag.x);
                a.y = fmaf(eps, vv.y, ag.y);
                a.z = fmaf(eps, vv.z, ag.z);
                a.w = fmaf(eps, vv.w, ag.w);
            }
            As[lc + 0][lr + h * 32] = a.x;
            As[lc + 1][lr + h * 32] = a.y;
            As[lc + 2][lr + h * 32] = a.z;
            As[lc + 3][lr + h * 32] = a.w;
        }
#pragma unroll
        for (int h = 0; h < 2; ++h) {
            int krow = kk + br + h * 16;
            *reinterpret_cast<float4*>(&Bs[br + h * 16][bc]) =
                *reinterpret_cast<const float4*>(w1 + (size_t)krow * D_HID + bn + bc);
        }
        __syncthreads();
#pragma unroll
        for (int k = 0; k < 32; ++k) {
            float4 a4 = *reinterpret_cast<float4*>(&As[k][ty * 4]);
            float4 b4 = *reinterpret_cast<float4*>(&Bs[k][tx * 4]);
            float af[4] = {a4.x, a4.y, a4.z, a4.w};
            float bf[4] = {b4.x, b4.y, b4.z, b4.w};
#pragma unroll
            for (int i = 0; i < 4; ++i)
#pragma unroll
                for (int j = 0; j < 4; ++j)
                    acc[i][j] = fmaf(af[i], bf[j], acc[i][j]);
        }
        __syncthreads();
    }
#pragma unroll
    for (int i = 0; i < 4; ++i) {
        int row = bm + ty * 4 + i;
        if (row < M) {
            float4 o = make_float4(acc[i][0], acc[i][1], acc[i][2], acc[i][3]);
            *reinterpret_cast<float4*>(y1 + (size_t)row * D_HID + bn + tx * 4) = o;
        }
    }
}

// ---------------------------------------------------------------------------
// 3) GEMM2: y2 = relu(y1*s1+t1) @ w2     [M,256]x[256,128] -> [M,128]
//    BN1+ReLU applied during A staging.
// ---------------------------------------------------------------------------
__global__ __launch_bounds__(256) void gemm2(
    const float* __restrict__ y1, const float2* __restrict__ f1,
    const float* __restrict__ w2, float* __restrict__ y2, int M)
{
    __shared__ __align__(16) float As[32][68];
    __shared__ __align__(16) float Bs[32][64];
    const int tid = threadIdx.x;
    const int bm = blockIdx.x * 64;
    const int bn = blockIdx.y * 64;
    const int lr = tid >> 3, lc = (tid & 7) << 2;
    const int br = tid >> 4, bc = (tid & 15) << 2;
    const int ty = tid >> 4, tx = tid & 15;
    float acc[4][4] = {};

    for (int kk = 0; kk < D_HID; kk += 32) {
#pragma unroll
        for (int h = 0; h < 2; ++h) {
            int row = bm + lr + h * 32;
            float4 a = make_float4(0.f, 0.f, 0.f, 0.f);
            if (row < M) {
                const float4 x = *reinterpret_cast<const float4*>(y1 + (size_t)row * D_HID + kk + lc);
                float2 fa = f1[kk + lc + 0];
                float2 fb = f1[kk + lc + 1];
                float2 fc = f1[kk + lc + 2];
                float2 fd = f1[kk + lc + 3];
                a.x = fmaxf(fmaf(x.x, fa.x, fa.y), 0.f);
                a.y = fmaxf(fmaf(x.y, fb.x, fb.y), 0.f);
                a.z = fmaxf(fmaf(x.z, fc.x, fc.y), 0.f);
                a.w = fmaxf(fmaf(x.w, fd.x, fd.y), 0.f);
            }
            As[lc + 0][lr + h * 32] = a.x;
            As[lc + 1][lr + h * 32] = a.y;
            As[lc + 2][lr + h * 32] = a.z;
            As[lc + 3][lr + h * 32] = a.w;
        }
#pragma unroll
        for (int h = 0; h < 2; ++h) {
            int krow = kk + br + h * 16;
            *reinterpret_cast<float4*>(&Bs[br + h * 16][bc]) =
                *reinterpret_cast<const float4*>(w2 + (size_t)krow * D_OUT + bn + bc);
        }
        __syncthreads();
#pragma unroll
        for (int k = 0; k < 32; ++k) {
            float4 a4 = *reinterpret_cast<float4*>(&As[k][ty * 4]);
            float4 b4 = *reinterpret_cast<float4*>(&Bs[k][tx * 4]);
            float af[4] = {a4.x, a4.y, a4.z, a4.w};
            float bf[4] = {b4.x, b4.y, b4.z, b4.w};
#pragma unroll
            for (int i = 0; i < 4; ++i)
#pragma unroll
                for (int j = 0; j < 4; ++j)
                    acc[i][j] = fmaf(af[i], bf[j], acc[i][j]);
        }
        __syncthreads();
    }
#pragma unroll
    for (int i = 0; i < 4; ++i) {
        int row = bm + ty * 4 + i;
        if (row < M) {
            float4 o = make_float4(acc[i][0], acc[i][1], acc[i][2], acc[i][3]);
            *reinterpret_cast<float4*>(y2 + (size_t)row * D_OUT + bn + tx * 4) = o;
        }
    }
}

// ---------------------------------------------------------------------------
// 4) column stats: sum / sumsq over rows (for BN batch stats)
// ---------------------------------------------------------------------------
template <int C>
__global__ void colstats(const float* __restrict__ y, int M,
                         float* __restrict__ sum, float* __restrict__ sq)
{
    const int col = threadIdx.x;          // blockDim == C
    const int r0 = blockIdx.x * 256;
    const int r1 = min(r0 + 256, M);
    float s = 0.f, q = 0.f;
    for (int r = r0; r < r1; ++r) {
        float x = y[(size_t)r * C + col];
        s += x;
        q = fmaf(x, x, q);
    }
    atomicAdd(&sum[col], s);
    atomicAdd(&sq[col], q);
}

// ---------------------------------------------------------------------------
// 5) BN factors: s = g*rsqrt(var+eps); t = be - mean*s   (bias cancels in BN)
// ---------------------------------------------------------------------------
__global__ void bnfactors(const float* __restrict__ sum, const float* __restrict__ sq,
                          const float* __restrict__ g, const float* __restrict__ be,
                          float2* __restrict__ f, int C, int M)
{
    int c = threadIdx.x;
    if (c < C) {
        float inv = 1.f / (float)M;
        float mean = sum[c] * inv;
        float var = fmaxf(sq[c] * inv - mean * mean, 0.f);
        float s = g[c] * rsqrtf(var + BN_EPS);
        f[c] = make_float2(s, be[c] - mean * s);
    }
}

// ---------------------------------------------------------------------------
// 6) final elementwise: out = relu(y2*s2 + t2)
// ---------------------------------------------------------------------------
__global__ __launch_bounds__(256) void bnrelu_out(
    const float* __restrict__ y2, const float2* __restrict__ f2,
    float* __restrict__ out, int total4)
{
    int i = blockIdx.x * 256 + threadIdx.x;
    if (i >= total4) return;
    float4 x = reinterpret_cast<const float4*>(y2)[i];
    int c = (i & (D_OUT / 4 - 1)) << 2;
    float2 fa = f2[c + 0];
    float2 fb = f2[c + 1];
    float2 fc = f2[c + 2];
    float2 fd = f2[c + 3];
    float4 o;
    o.x = fmaxf(fmaf(x.x, fa.x, fa.y), 0.f);
    o.y = fmaxf(fmaf(x.y, fb.x, fb.y), 0.f);
    o.z = fmaxf(fmaf(x.z, fc.x, fc.y), 0.f);
    o.w = fmaxf(fmaf(x.w, fd.x, fd.y), 0.f);
    reinterpret_cast<float4*>(out)[i] = o;
}

// ---------------------------------------------------------------------------
extern "C" void kernel_launch(void* const* d_in, const int* in_sizes, int n_in,
                              void* d_out, int out_size, void* d_ws, size_t ws_size,
                              hipStream_t stream)
{
    const float* v     = (const float*)d_in[0];
    const int*   erows = (const int*)d_in[1];
    const int*   ecols = (const int*)d_in[2];
    const float* evals = (const float*)d_in[3];
    const float* w1    = (const float*)d_in[4];
    // b1 = d_in[5], b2 = d_in[9]: linear bias cancels exactly inside BatchNorm.
    const float* g1    = (const float*)d_in[6];
    const float* be1   = (const float*)d_in[7];
    const float* w2    = (const float*)d_in[8];
    const float* g2    = (const float*)d_in[10];
    const float* be2   = (const float*)d_in[11];
    const float* eps   = (const float*)d_in[12];

    const int M = in_sizes[0] / D_IN;   // 50000
    const int E = in_sizes[3];          // 800000

    float* ws   = (float*)d_ws;
    float* agg  = ws;                               // M*128
    float* y1   = agg + (size_t)M * D_IN;           // M*256
    float* st   = y1 + (size_t)M * D_HID;           // stats
    float* sum1 = st;
    float* sq1  = sum1 + D_HID;
    float* sum2 = sq1 + D_HID;
    float* sq2  = sum2 + D_OUT;
    float2* f1  = (float2*)(sq2 + D_OUT);           // 256 float2
    float2* f2  = f1 + D_HID;                       // 128 float2
    float* y2   = agg;                              // alias: agg dead after GEMM1
    float* outp = (float*)d_out;

    hipMemsetAsync(agg, 0, (size_t)M * D_IN * sizeof(float), stream);
    hipMemsetAsync(st, 0, (size_t)(2 * D_HID + 2 * D_OUT) * sizeof(float), stream);

    spmm_scatter<<<(E * 32 + 255) / 256, 256, 0, stream>>>(v, erows, ecols, evals, agg, E);

    dim3 grid1((M + 63) / 64, D_HID / 64);
    gemm1<<<grid1, 256, 0, stream>>>(agg, v, eps, w1, y1, M);

    colstats<D_HID><<<(M + 255) / 256, D_HID, 0, stream>>>(y1, M, sum1, sq1);
    bnfactors<<<1, D_HID, 0, stream>>>(sum1, sq1, g1, be1, f1, D_HID, M);

    dim3 grid2((M + 63) / 64, D_OUT / 64);
    gemm2<<<grid2, 256, 0, stream>>>(y1, f1, w2, y2, M);

    colstats<D_OUT><<<(M + 255) / 256, D_OUT, 0, stream>>>(y2, M, sum2, sq2);
    bnfactors<<<1, D_OUT, 0, stream>>>(sum2, sq2, g2, be2, f2, D_OUT, M);

    bnrelu_out<<<(M * D_OUT / 4 + 255) / 256, 256, 0, stream>>>(y2, f2, outp, M * D_OUT / 4);
}

// Round 4
// 597.049 us; speedup vs baseline: 2.8141x; 2.8141x over previous
//
#include <hip/hip_runtime.h>

#define D_IN 128
#define D_HID 256
#define D_OUT 128
#define BN_EPS 1e-5f
#define NNODES 50000

// ---------------------------------------------------------------------------
// 1) histogram: cnt[rows[e]]++  (int atomics on 200 KB — cheap)
// ---------------------------------------------------------------------------
__global__ __launch_bounds__(256) void edge_hist(
    const int* __restrict__ rows, int* __restrict__ cnt, int E)
{
    int e = blockIdx.x * 256 + threadIdx.x;
    if (e < E) atomicAdd(&cnt[rows[e]], 1);
}

// ---------------------------------------------------------------------------
// 2) one-block exclusive scan over N counts -> rowstart[N+1], cursor[N]
// ---------------------------------------------------------------------------
__global__ __launch_bounds__(1024) void scan_counts(
    const int* __restrict__ cnt, int* __restrict__ rowstart,
    int* __restrict__ cursor, int N, int E)
{
    __shared__ int sdata[1024];
    const int t = threadIdx.x;
    const int chunk = (N + 1023) / 1024;
    const int lo = t * chunk, hi = min(lo + chunk, N);
    int s = 0;
    for (int i = lo; i < hi; ++i) s += cnt[i];
    sdata[t] = s;
    __syncthreads();
    for (int off = 1; off < 1024; off <<= 1) {
        int x = (t >= off) ? sdata[t - off] : 0;
        __syncthreads();
        sdata[t] += x;
        __syncthreads();
    }
    int running = sdata[t] - s;   // exclusive prefix of this chunk
    for (int i = lo; i < hi; ++i) {
        int c = cnt[i];
        rowstart[i] = running;
        cursor[i] = running;
        running += c;
    }
    if (t == 0) rowstart[N] = E;
}

// ---------------------------------------------------------------------------
// 3) scatter edges into row-bucketed order: ecv[pos] = (col, val)
// ---------------------------------------------------------------------------
__global__ __launch_bounds__(256) void edge_scatter(
    const int* __restrict__ rows, const int* __restrict__ cols,
    const float* __restrict__ vals, int* __restrict__ cursor,
    float2* __restrict__ ecv, int E)
{
    int e = blockIdx.x * 256 + threadIdx.x;
    if (e >= E) return;
    int r = rows[e];
    int pos = atomicAdd(&cursor[r], 1);
    ecv[pos] = make_float2(__int_as_float(cols[e]), vals[e]);
}

// ---------------------------------------------------------------------------
// 4) gather-aggregate: one wave per row.
//    agg[r] = sum_e val_e * v[col_e]; every row written (no memset needed).
// ---------------------------------------------------------------------------
__global__ __launch_bounds__(256) void spmm_rows(
    const float* __restrict__ v, const int* __restrict__ rowstart,
    const float2* __restrict__ ecv, float* __restrict__ agg, int N)
{
    int wid = (blockIdx.x * 256 + threadIdx.x) >> 6;   // wave id == row
    if (wid >= N) return;
    int lane = threadIdx.x & 63;
    int s = rowstart[wid], e = rowstart[wid + 1];
    float accx = 0.f, accy = 0.f;
    for (int base = s; base < e; base += 64) {
        int n = min(64, e - base);
        float2 ev = make_float2(0.f, 0.f);
        if (base + lane < e) ev = ecv[base + lane];
        int mycol = __float_as_int(ev.x);
        for (int k = 0; k < n; ++k) {
            int col = __shfl(mycol, k);
            float val = __shfl(ev.y, k);
            const float2 vv = *reinterpret_cast<const float2*>(
                v + (size_t)col * D_IN + lane * 2);
            accx = fmaf(val, vv.x, accx);
            accy = fmaf(val, vv.y, accy);
        }
    }
    *reinterpret_cast<float2*>(agg + (size_t)wid * D_IN + lane * 2) =
        make_float2(accx, accy);
}

// ---------------------------------------------------------------------------
// 5) GEMM1: y1 = (agg + eps*v) @ w1      [M,128]x[128,256] -> [M,256]
// ---------------------------------------------------------------------------
__global__ __launch_bounds__(256) void gemm1(
    const float* __restrict__ agg, const float* __restrict__ v,
    const float* __restrict__ epsp, const float* __restrict__ w1,
    float* __restrict__ y1, int M)
{
    __shared__ __align__(16) float As[32][68];
    __shared__ __align__(16) float Bs[32][64];
    const int tid = threadIdx.x;
    const int bm = blockIdx.x * 64;
    const int bn = blockIdx.y * 64;
    const float eps = *epsp;
    const int lr = tid >> 3, lc = (tid & 7) << 2;
    const int br = tid >> 4, bc = (tid & 15) << 2;
    const int ty = tid >> 4, tx = tid & 15;
    float acc[4][4] = {};

    for (int kk = 0; kk < D_IN; kk += 32) {
#pragma unroll
        for (int h = 0; h < 2; ++h) {
            int row = bm + lr + h * 32;
            float4 a = make_float4(0.f, 0.f, 0.f, 0.f);
            if (row < M) {
                const float4 ag = *reinterpret_cast<const float4*>(agg + (size_t)row * D_IN + kk + lc);
                const float4 vv = *reinterpret_cast<const float4*>(v + (size_t)row * D_IN + kk + lc);
                a.x = fmaf(eps, vv.x, ag.x);
                a.y = fmaf(eps, vv.y, ag.y);
                a.z = fmaf(eps, vv.z, ag.z);
                a.w = fmaf(eps, vv.w, ag.w);
            }
            As[lc + 0][lr + h * 32] = a.x;
            As[lc + 1][lr + h * 32] = a.y;
            As[lc + 2][lr + h * 32] = a.z;
            As[lc + 3][lr + h * 32] = a.w;
        }
#pragma unroll
        for (int h = 0; h < 2; ++h) {
            int krow = kk + br + h * 16;
            *reinterpret_cast<float4*>(&Bs[br + h * 16][bc]) =
                *reinterpret_cast<const float4*>(w1 + (size_t)krow * D_HID + bn + bc);
        }
        __syncthreads();
#pragma unroll
        for (int k = 0; k < 32; ++k) {
            float4 a4 = *reinterpret_cast<float4*>(&As[k][ty * 4]);
            float4 b4 = *reinterpret_cast<float4*>(&Bs[k][tx * 4]);
            float af[4] = {a4.x, a4.y, a4.z, a4.w};
            float bf[4] = {b4.x, b4.y, b4.z, b4.w};
#pragma unroll
            for (int i = 0; i < 4; ++i)
#pragma unroll
                for (int j = 0; j < 4; ++j)
                    acc[i][j] = fmaf(af[i], bf[j], acc[i][j]);
        }
        __syncthreads();
    }
#pragma unroll
    for (int i = 0; i < 4; ++i) {
        int row = bm + ty * 4 + i;
        if (row < M) {
            float4 o = make_float4(acc[i][0], acc[i][1], acc[i][2], acc[i][3]);
            *reinterpret_cast<float4*>(y1 + (size_t)row * D_HID + bn + tx * 4) = o;
        }
    }
}

// ---------------------------------------------------------------------------
// 6) GEMM2: y2 = relu(y1*s1+t1) @ w2     (BN1+ReLU fused into A staging)
// ---------------------------------------------------------------------------
__global__ __launch_bounds__(256) void gemm2(
    const float* __restrict__ y1, const float2* __restrict__ f1,
    const float* __restrict__ w2, float* __restrict__ y2, int M)
{
    __shared__ __align__(16) float As[32][68];
    __shared__ __align__(16) float Bs[32][64];
    const int tid = threadIdx.x;
    const int bm = blockIdx.x * 64;
    const int bn = blockIdx.y * 64;
    const int lr = tid >> 3, lc = (tid & 7) << 2;
    const int br = tid >> 4, bc = (tid & 15) << 2;
    const int ty = tid >> 4, tx = tid & 15;
    float acc[4][4] = {};

    for (int kk = 0; kk < D_HID; kk += 32) {
#pragma unroll
        for (int h = 0; h < 2; ++h) {
            int row = bm + lr + h * 32;
            float4 a = make_float4(0.f, 0.f, 0.f, 0.f);
            if (row < M) {
                const float4 x = *reinterpret_cast<const float4*>(y1 + (size_t)row * D_HID + kk + lc);
                float2 fa = f1[kk + lc + 0];
                float2 fb = f1[kk + lc + 1];
                float2 fc = f1[kk + lc + 2];
                float2 fd = f1[kk + lc + 3];
                a.x = fmaxf(fmaf(x.x, fa.x, fa.y), 0.f);
                a.y = fmaxf(fmaf(x.y, fb.x, fb.y), 0.f);
                a.z = fmaxf(fmaf(x.z, fc.x, fc.y), 0.f);
                a.w = fmaxf(fmaf(x.w, fd.x, fd.y), 0.f);
            }
            As[lc + 0][lr + h * 32] = a.x;
            As[lc + 1][lr + h * 32] = a.y;
            As[lc + 2][lr + h * 32] = a.z;
            As[lc + 3][lr + h * 32] = a.w;
        }
#pragma unroll
        for (int h = 0; h < 2; ++h) {
            int krow = kk + br + h * 16;
            *reinterpret_cast<float4*>(&Bs[br + h * 16][bc]) =
                *reinterpret_cast<const float4*>(w2 + (size_t)krow * D_OUT + bn + bc);
        }
        __syncthreads();
#pragma unroll
        for (int k = 0; k < 32; ++k) {
            float4 a4 = *reinterpret_cast<float4*>(&As[k][ty * 4]);
            float4 b4 = *reinterpret_cast<float4*>(&Bs[k][tx * 4]);
            float af[4] = {a4.x, a4.y, a4.z, a4.w};
            float bf[4] = {b4.x, b4.y, b4.z, b4.w};
#pragma unroll
            for (int i = 0; i < 4; ++i)
#pragma unroll
                for (int j = 0; j < 4; ++j)
                    acc[i][j] = fmaf(af[i], bf[j], acc[i][j]);
        }
        __syncthreads();
    }
#pragma unroll
    for (int i = 0; i < 4; ++i) {
        int row = bm + ty * 4 + i;
        if (row < M) {
            float4 o = make_float4(acc[i][0], acc[i][1], acc[i][2], acc[i][3]);
            *reinterpret_cast<float4*>(y2 + (size_t)row * D_OUT + bn + tx * 4) = o;
        }
    }
}

// ---------------------------------------------------------------------------
// 7) column stats: sum / sumsq over rows (for BN batch stats)
// ---------------------------------------------------------------------------
template <int C>
__global__ void colstats(const float* __restrict__ y, int M,
                         float* __restrict__ sum, float* __restrict__ sq)
{
    const int col = threadIdx.x;          // blockDim == C
    const int r0 = blockIdx.x * 256;
    const int r1 = min(r0 + 256, M);
    float s = 0.f, q = 0.f;
    for (int r = r0; r < r1; ++r) {
        float x = y[(size_t)r * C + col];
        s += x;
        q = fmaf(x, x, q);
    }
    atomicAdd(&sum[col], s);
    atomicAdd(&sq[col], q);
}

// ---------------------------------------------------------------------------
// 8) BN factors: s = g*rsqrt(var+eps); t = be - mean*s   (bias cancels in BN)
// ---------------------------------------------------------------------------
__global__ void bnfactors(const float* __restrict__ sum, const float* __restrict__ sq,
                          const float* __restrict__ g, const float* __restrict__ be,
                          float2* __restrict__ f, int C, int M)
{
    int c = threadIdx.x;
    if (c < C) {
        float inv = 1.f / (float)M;
        float mean = sum[c] * inv;
        float var = fmaxf(sq[c] * inv - mean * mean, 0.f);
        float s = g[c] * rsqrtf(var + BN_EPS);
        f[c] = make_float2(s, be[c] - mean * s);
    }
}

// ---------------------------------------------------------------------------
// 9) final elementwise: out = relu(y2*s2 + t2)
// ---------------------------------------------------------------------------
__global__ __launch_bounds__(256) void bnrelu_out(
    const float* __restrict__ y2, const float2* __restrict__ f2,
    float* __restrict__ out, int total4)
{
    int i = blockIdx.x * 256 + threadIdx.x;
    if (i >= total4) return;
    float4 x = reinterpret_cast<const float4*>(y2)[i];
    int c = (i & (D_OUT / 4 - 1)) << 2;
    float2 fa = f2[c + 0];
    float2 fb = f2[c + 1];
    float2 fc = f2[c + 2];
    float2 fd = f2[c + 3];
    float4 o;
    o.x = fmaxf(fmaf(x.x, fa.x, fa.y), 0.f);
    o.y = fmaxf(fmaf(x.y, fb.x, fb.y), 0.f);
    o.z = fmaxf(fmaf(x.z, fc.x, fc.y), 0.f);
    o.w = fmaxf(fmaf(x.w, fd.x, fd.y), 0.f);
    reinterpret_cast<float4*>(out)[i] = o;
}

// ---------------------------------------------------------------------------
extern "C" void kernel_launch(void* const* d_in, const int* in_sizes, int n_in,
                              void* d_out, int out_size, void* d_ws, size_t ws_size,
                              hipStream_t stream)
{
    const float* v     = (const float*)d_in[0];
    const int*   erows = (const int*)d_in[1];
    const int*   ecols = (const int*)d_in[2];
    const float* evals = (const float*)d_in[3];
    const float* w1    = (const float*)d_in[4];
    // b1 = d_in[5], b2 = d_in[9]: linear bias cancels exactly inside BatchNorm.
    const float* g1    = (const float*)d_in[6];
    const float* be1   = (const float*)d_in[7];
    const float* w2    = (const float*)d_in[8];
    const float* g2    = (const float*)d_in[10];
    const float* be2   = (const float*)d_in[11];
    const float* eps   = (const float*)d_in[12];

    const int M = in_sizes[0] / D_IN;   // 50000
    const int E = in_sizes[3];          // 800000

    float* ws   = (float*)d_ws;
    float* agg  = ws;                               // M*128
    float* y1   = agg + (size_t)M * D_IN;           // M*256
    int*  rowstart = (int*)(y1 + (size_t)M * D_HID); // N+1
    int*  cursor   = rowstart + M + 2;              // N (pad keeps 8B align)
    int*  cnthist  = cursor + M;                    // N counts
    // pad to even 4-byte units for float2 alignment
    size_t ecv_ofs = ((size_t)(cnthist + M - (int*)ws) + 1) & ~(size_t)1;
    float2* ecv = (float2*)((float*)ws + ecv_ofs);  // E float2
    float* st   = (float*)(ecv + E);
    float* sum1 = st;
    float* sq1  = sum1 + D_HID;
    float* sum2 = sq1 + D_HID;
    float* sq2  = sum2 + D_OUT;
    float2* f1  = (float2*)(sq2 + D_OUT);           // 256 float2
    float2* f2  = f1 + D_HID;                       // 128 float2
    float* y2   = agg;                              // alias: agg dead after GEMM1
    float* outp = (float*)d_out;

    hipMemsetAsync(cnthist, 0, (size_t)M * sizeof(int), stream);
    hipMemsetAsync(st, 0, (size_t)(2 * D_HID + 2 * D_OUT) * sizeof(float), stream);

    edge_hist<<<(E + 255) / 256, 256, 0, stream>>>(erows, cnthist, E);
    scan_counts<<<1, 1024, 0, stream>>>(cnthist, rowstart, cursor, M, E);
    edge_scatter<<<(E + 255) / 256, 256, 0, stream>>>(erows, ecols, evals, cursor, ecv, E);
    spmm_rows<<<(M * 64 + 255) / 256, 256, 0, stream>>>(v, rowstart, ecv, agg, M);

    dim3 grid1((M + 63) / 64, D_HID / 64);
    gemm1<<<grid1, 256, 0, stream>>>(agg, v, eps, w1, y1, M);

    colstats<D_HID><<<(M + 255) / 256, D_HID, 0, stream>>>(y1, M, sum1, sq1);
    bnfactors<<<1, D_HID, 0, stream>>>(sum1, sq1, g1, be1, f1, D_HID, M);

    dim3 grid2((M + 63) / 64, D_OUT / 64);
    gemm2<<<grid2, 256, 0, stream>>>(y1, f1, w2, y2, M);

    colstats<D_OUT><<<(M + 255) / 256, D_OUT, 0, stream>>>(y2, M, sum2, sq2);
    bnfactors<<<1, D_OUT, 0, stream>>>(sum2, sq2, g2, be2, f2, D_OUT, M);

    bnrelu_out<<<(M * D_OUT / 4 + 255) / 256, 256, 0, stream>>>(y2, f2, outp, M * D_OUT / 4);
}

// Round 5
// 498.529 us; speedup vs baseline: 3.3702x; 1.1976x over previous
//
#include <hip/hip_runtime.h>

#define D_IN 128
#define D_HID 256
#define D_OUT 128
#define BN_EPS 1e-5f

// ---------------------------------------------------------------------------
// 1) histogram: cnt[rows[e]]++  (int atomics on 200 KB — cheap)
// ---------------------------------------------------------------------------
__global__ __launch_bounds__(256) void edge_hist(
    const int* __restrict__ rows, int* __restrict__ cnt, int E)
{
    int e = blockIdx.x * 256 + threadIdx.x;
    if (e < E) atomicAdd(&cnt[rows[e]], 1);
}

// ---------------------------------------------------------------------------
// 2a) per-chunk sums: bsum[b] = sum of cnt[b*256 .. b*256+255]  (coalesced)
// ---------------------------------------------------------------------------
__global__ __launch_bounds__(256) void chunk_sums(
    const int* __restrict__ cnt, int* __restrict__ bsum, int N)
{
    __shared__ int red[256];
    const int t = threadIdx.x;
    const int i = blockIdx.x * 256 + t;
    red[t] = (i < N) ? cnt[i] : 0;
    __syncthreads();
#pragma unroll
    for (int off = 128; off > 0; off >>= 1) {
        if (t < off) red[t] += red[t + off];
        __syncthreads();
    }
    if (t == 0) bsum[blockIdx.x] = red[0];
}

// ---------------------------------------------------------------------------
// 2b) scan chunk sums (NB <= 256): coff[b] = exclusive prefix of bsum
// ---------------------------------------------------------------------------
__global__ __launch_bounds__(256) void scan_chunks(
    const int* __restrict__ bsum, int* __restrict__ coff, int NB)
{
    __shared__ int s[256];
    const int t = threadIdx.x;
    int c = (t < NB) ? bsum[t] : 0;
    s[t] = c;
    __syncthreads();
#pragma unroll
    for (int off = 1; off < 256; off <<= 1) {
        int x = (t >= off) ? s[t - off] : 0;
        __syncthreads();
        s[t] += x;
        __syncthreads();
    }
    coff[t] = s[t] - c;   // exclusive
}

// ---------------------------------------------------------------------------
// 2c) block-local scan + chunk offset -> rowstart[N+1], cursor[N]
// ---------------------------------------------------------------------------
__global__ __launch_bounds__(256) void scan_write(
    const int* __restrict__ cnt, const int* __restrict__ coff,
    int* __restrict__ rowstart, int* __restrict__ cursor, int N)
{
    __shared__ int s[256];
    const int t = threadIdx.x;
    const int i = blockIdx.x * 256 + t;
    int c = (i < N) ? cnt[i] : 0;
    s[t] = c;
    __syncthreads();
#pragma unroll
    for (int off = 1; off < 256; off <<= 1) {
        int x = (t >= off) ? s[t - off] : 0;
        __syncthreads();
        s[t] += x;
        __syncthreads();
    }
    int pos = coff[blockIdx.x] + s[t] - c;   // global exclusive prefix
    if (i < N) {
        rowstart[i] = pos;
        cursor[i] = pos;
    } else if (i == N) {
        rowstart[N] = pos;                   // == E
    }
}

// ---------------------------------------------------------------------------
// 3) scatter edges into row-bucketed order: ecv[pos] = (col, val)
// ---------------------------------------------------------------------------
__global__ __launch_bounds__(256) void edge_scatter(
    const int* __restrict__ rows, const int* __restrict__ cols,
    const float* __restrict__ vals, int* __restrict__ cursor,
    float2* __restrict__ ecv, int E)
{
    int e = blockIdx.x * 256 + threadIdx.x;
    if (e >= E) return;
    int r = rows[e];
    int pos = atomicAdd(&cursor[r], 1);
    ecv[pos] = make_float2(__int_as_float(cols[e]), vals[e]);
}

// ---------------------------------------------------------------------------
// 4) gather-aggregate: one wave per row.
//    agg[r] = sum_e val_e * v[col_e]; every row written (no memset needed).
// ---------------------------------------------------------------------------
__global__ __launch_bounds__(256) void spmm_rows(
    const float* __restrict__ v, const int* __restrict__ rowstart,
    const float2* __restrict__ ecv, float* __restrict__ agg, int N)
{
    int wid = (blockIdx.x * 256 + threadIdx.x) >> 6;   // wave id == row
    if (wid >= N) return;
    int lane = threadIdx.x & 63;
    int s = rowstart[wid], e = rowstart[wid + 1];
    float accx = 0.f, accy = 0.f;
    for (int base = s; base < e; base += 64) {
        int n = min(64, e - base);
        float2 ev = make_float2(0.f, 0.f);
        if (base + lane < e) ev = ecv[base + lane];
        int mycol = __float_as_int(ev.x);
        for (int k = 0; k < n; ++k) {
            int col = __shfl(mycol, k);
            float val = __shfl(ev.y, k);
            const float2 vv = *reinterpret_cast<const float2*>(
                v + (size_t)col * D_IN + lane * 2);
            accx = fmaf(val, vv.x, accx);
            accy = fmaf(val, vv.y, accy);
        }
    }
    *reinterpret_cast<float2*>(agg + (size_t)wid * D_IN + lane * 2) =
        make_float2(accx, accy);
}

// ---------------------------------------------------------------------------
// 5) GEMM1: y1 = (agg + eps*v) @ w1      [M,128]x[128,256] -> [M,256]
// ---------------------------------------------------------------------------
__global__ __launch_bounds__(256) void gemm1(
    const float* __restrict__ agg, const float* __restrict__ v,
    const float* __restrict__ epsp, const float* __restrict__ w1,
    float* __restrict__ y1, int M)
{
    __shared__ __align__(16) float As[32][68];
    __shared__ __align__(16) float Bs[32][64];
    const int tid = threadIdx.x;
    const int bm = blockIdx.x * 64;
    const int bn = blockIdx.y * 64;
    const float eps = *epsp;
    const int lr = tid >> 3, lc = (tid & 7) << 2;
    const int br = tid >> 4, bc = (tid & 15) << 2;
    const int ty = tid >> 4, tx = tid & 15;
    float acc[4][4] = {};

    for (int kk = 0; kk < D_IN; kk += 32) {
#pragma unroll
        for (int h = 0; h < 2; ++h) {
            int row = bm + lr + h * 32;
            float4 a = make_float4(0.f, 0.f, 0.f, 0.f);
            if (row < M) {
                const float4 ag = *reinterpret_cast<const float4*>(agg + (size_t)row * D_IN + kk + lc);
                const float4 vv = *reinterpret_cast<const float4*>(v + (size_t)row * D_IN + kk + lc);
                a.x = fmaf(eps, vv.x, ag.x);
                a.y = fmaf(eps, vv.y, ag.y);
                a.z = fmaf(eps, vv.z, ag.z);
                a.w = fmaf(eps, vv.w, ag.w);
            }
            As[lc + 0][lr + h * 32] = a.x;
            As[lc + 1][lr + h * 32] = a.y;
            As[lc + 2][lr + h * 32] = a.z;
            As[lc + 3][lr + h * 32] = a.w;
        }
#pragma unroll
        for (int h = 0; h < 2; ++h) {
            int krow = kk + br + h * 16;
            *reinterpret_cast<float4*>(&Bs[br + h * 16][bc]) =
                *reinterpret_cast<const float4*>(w1 + (size_t)krow * D_HID + bn + bc);
        }
        __syncthreads();
#pragma unroll
        for (int k = 0; k < 32; ++k) {
            float4 a4 = *reinterpret_cast<float4*>(&As[k][ty * 4]);
            float4 b4 = *reinterpret_cast<float4*>(&Bs[k][tx * 4]);
            float af[4] = {a4.x, a4.y, a4.z, a4.w};
            float bf[4] = {b4.x, b4.y, b4.z, b4.w};
#pragma unroll
            for (int i = 0; i < 4; ++i)
#pragma unroll
                for (int j = 0; j < 4; ++j)
                    acc[i][j] = fmaf(af[i], bf[j], acc[i][j]);
        }
        __syncthreads();
    }
#pragma unroll
    for (int i = 0; i < 4; ++i) {
        int row = bm + ty * 4 + i;
        if (row < M) {
            float4 o = make_float4(acc[i][0], acc[i][1], acc[i][2], acc[i][3]);
            *reinterpret_cast<float4*>(y1 + (size_t)row * D_HID + bn + tx * 4) = o;
        }
    }
}

// ---------------------------------------------------------------------------
// 6) GEMM2: y2 = relu(y1*s1+t1) @ w2     (BN1+ReLU fused into A staging)
// ---------------------------------------------------------------------------
__global__ __launch_bounds__(256) void gemm2(
    const float* __restrict__ y1, const float2* __restrict__ f1,
    const float* __restrict__ w2, float* __restrict__ y2, int M)
{
    __shared__ __align__(16) float As[32][68];
    __shared__ __align__(16) float Bs[32][64];
    const int tid = threadIdx.x;
    const int bm = blockIdx.x * 64;
    const int bn = blockIdx.y * 64;
    const int lr = tid >> 3, lc = (tid & 7) << 2;
    const int br = tid >> 4, bc = (tid & 15) << 2;
    const int ty = tid >> 4, tx = tid & 15;
    float acc[4][4] = {};

    for (int kk = 0; kk < D_HID; kk += 32) {
#pragma unroll
        for (int h = 0; h < 2; ++h) {
            int row = bm + lr + h * 32;
            float4 a = make_float4(0.f, 0.f, 0.f, 0.f);
            if (row < M) {
                const float4 x = *reinterpret_cast<const float4*>(y1 + (size_t)row * D_HID + kk + lc);
                float2 fa = f1[kk + lc + 0];
                float2 fb = f1[kk + lc + 1];
                float2 fc = f1[kk + lc + 2];
                float2 fd = f1[kk + lc + 3];
                a.x = fmaxf(fmaf(x.x, fa.x, fa.y), 0.f);
                a.y = fmaxf(fmaf(x.y, fb.x, fb.y), 0.f);
                a.z = fmaxf(fmaf(x.z, fc.x, fc.y), 0.f);
                a.w = fmaxf(fmaf(x.w, fd.x, fd.y), 0.f);
            }
            As[lc + 0][lr + h * 32] = a.x;
            As[lc + 1][lr + h * 32] = a.y;
            As[lc + 2][lr + h * 32] = a.z;
            As[lc + 3][lr + h * 32] = a.w;
        }
#pragma unroll
        for (int h = 0; h < 2; ++h) {
            int krow = kk + br + h * 16;
            *reinterpret_cast<float4*>(&Bs[br + h * 16][bc]) =
                *reinterpret_cast<const float4*>(w2 + (size_t)krow * D_OUT + bn + bc);
        }
        __syncthreads();
#pragma unroll
        for (int k = 0; k < 32; ++k) {
            float4 a4 = *reinterpret_cast<float4*>(&As[k][ty * 4]);
            float4 b4 = *reinterpret_cast<float4*>(&Bs[k][tx * 4]);
            float af[4] = {a4.x, a4.y, a4.z, a4.w};
            float bf[4] = {b4.x, b4.y, b4.z, b4.w};
#pragma unroll
            for (int i = 0; i < 4; ++i)
#pragma unroll
                for (int j = 0; j < 4; ++j)
                    acc[i][j] = fmaf(af[i], bf[j], acc[i][j]);
        }
        __syncthreads();
    }
#pragma unroll
    for (int i = 0; i < 4; ++i) {
        int row = bm + ty * 4 + i;
        if (row < M) {
            float4 o = make_float4(acc[i][0], acc[i][1], acc[i][2], acc[i][3]);
            *reinterpret_cast<float4*>(y2 + (size_t)row * D_OUT + bn + tx * 4) = o;
        }
    }
}

// ---------------------------------------------------------------------------
// 7) column stats: sum / sumsq over rows (for BN batch stats)
// ---------------------------------------------------------------------------
template <int C>
__global__ void colstats(const float* __restrict__ y, int M,
                         float* __restrict__ sum, float* __restrict__ sq)
{
    const int col = threadIdx.x;          // blockDim == C
    const int r0 = blockIdx.x * 256;
    const int r1 = min(r0 + 256, M);
    float s = 0.f, q = 0.f;
    for (int r = r0; r < r1; ++r) {
        float x = y[(size_t)r * C + col];
        s += x;
        q = fmaf(x, x, q);
    }
    atomicAdd(&sum[col], s);
    atomicAdd(&sq[col], q);
}

// ---------------------------------------------------------------------------
// 8) BN factors: s = g*rsqrt(var+eps); t = be - mean*s   (bias cancels in BN)
// ---------------------------------------------------------------------------
__global__ void bnfactors(const float* __restrict__ sum, const float* __restrict__ sq,
                          const float* __restrict__ g, const float* __restrict__ be,
                          float2* __restrict__ f, int C, int M)
{
    int c = threadIdx.x;
    if (c < C) {
        float inv = 1.f / (float)M;
        float mean = sum[c] * inv;
        float var = fmaxf(sq[c] * inv - mean * mean, 0.f);
        float s = g[c] * rsqrtf(var + BN_EPS);
        f[c] = make_float2(s, be[c] - mean * s);
    }
}

// ---------------------------------------------------------------------------
// 9) final elementwise: out = relu(y2*s2 + t2)
// ---------------------------------------------------------------------------
__global__ __launch_bounds__(256) void bnrelu_out(
    const float* __restrict__ y2, const float2* __restrict__ f2,
    float* __restrict__ out, int total4)
{
    int i = blockIdx.x * 256 + threadIdx.x;
    if (i >= total4) return;
    float4 x = reinterpret_cast<const float4*>(y2)[i];
    int c = (i & (D_OUT / 4 - 1)) << 2;
    float2 fa = f2[c + 0];
    float2 fb = f2[c + 1];
    float2 fc = f2[c + 2];
    float2 fd = f2[c + 3];
    float4 o;
    o.x = fmaxf(fmaf(x.x, fa.x, fa.y), 0.f);
    o.y = fmaxf(fmaf(x.y, fb.x, fb.y), 0.f);
    o.z = fmaxf(fmaf(x.z, fc.x, fc.y), 0.f);
    o.w = fmaxf(fmaf(x.w, fd.x, fd.y), 0.f);
    reinterpret_cast<float4*>(out)[i] = o;
}

// ---------------------------------------------------------------------------
extern "C" void kernel_launch(void* const* d_in, const int* in_sizes, int n_in,
                              void* d_out, int out_size, void* d_ws, size_t ws_size,
                              hipStream_t stream)
{
    const float* v     = (const float*)d_in[0];
    const int*   erows = (const int*)d_in[1];
    const int*   ecols = (const int*)d_in[2];
    const float* evals = (const float*)d_in[3];
    const float* w1    = (const float*)d_in[4];
    // b1 = d_in[5], b2 = d_in[9]: linear bias cancels exactly inside BatchNorm.
    const float* g1    = (const float*)d_in[6];
    const float* be1   = (const float*)d_in[7];
    const float* w2    = (const float*)d_in[8];
    const float* g2    = (const float*)d_in[10];
    const float* be2   = (const float*)d_in[11];
    const float* eps   = (const float*)d_in[12];

    const int M = in_sizes[0] / D_IN;   // 50000
    const int E = in_sizes[3];          // 800000
    const int NB = (M + 255) / 256;     // 196 chunks (NB <= 256 required)

    float* ws   = (float*)d_ws;
    float* agg  = ws;                               // M*128
    float* y1   = agg + (size_t)M * D_IN;           // M*256
    int*  rowstart = (int*)(y1 + (size_t)M * D_HID); // N+1
    int*  cursor   = rowstart + M + 2;              // N (pad keeps 8B align)
    int*  cnthist  = cursor + M;                    // N counts
    int*  bsum     = cnthist + M;                   // 256 chunk sums
    int*  coff     = bsum + 256;                    // 256 chunk offsets
    // pad to even 4-byte units for float2 alignment
    size_t ecv_ofs = ((size_t)(coff + 256 - (int*)ws) + 1) & ~(size_t)1;
    float2* ecv = (float2*)((float*)ws + ecv_ofs);  // E float2
    float* st   = (float*)(ecv + E);
    float* sum1 = st;
    float* sq1  = sum1 + D_HID;
    float* sum2 = sq1 + D_HID;
    float* sq2  = sum2 + D_OUT;
    float2* f1  = (float2*)(sq2 + D_OUT);           // 256 float2
    float2* f2  = f1 + D_HID;                       // 128 float2
    float* y2   = agg;                              // alias: agg dead after GEMM1
    float* outp = (float*)d_out;

    hipMemsetAsync(cnthist, 0, (size_t)M * sizeof(int), stream);
    hipMemsetAsync(st, 0, (size_t)(2 * D_HID + 2 * D_OUT) * sizeof(float), stream);

    edge_hist<<<(E + 255) / 256, 256, 0, stream>>>(erows, cnthist, E);
    chunk_sums<<<NB, 256, 0, stream>>>(cnthist, bsum, M);
    scan_chunks<<<1, 256, 0, stream>>>(bsum, coff, NB);
    scan_write<<<NB, 256, 0, stream>>>(cnthist, coff, rowstart, cursor, M);
    edge_scatter<<<(E + 255) / 256, 256, 0, stream>>>(erows, ecols, evals, cursor, ecv, E);
    spmm_rows<<<(M * 64 + 255) / 256, 256, 0, stream>>>(v, rowstart, ecv, agg, M);

    dim3 grid1((M + 63) / 64, D_HID / 64);
    gemm1<<<grid1, 256, 0, stream>>>(agg, v, eps, w1, y1, M);

    colstats<D_HID><<<(M + 255) / 256, D_HID, 0, stream>>>(y1, M, sum1, sq1);
    bnfactors<<<1, D_HID, 0, stream>>>(sum1, sq1, g1, be1, f1, D_HID, M);

    dim3 grid2((M + 63) / 64, D_OUT / 64);
    gemm2<<<grid2, 256, 0, stream>>>(y1, f1, w2, y2, M);

    colstats<D_OUT><<<(M + 255) / 256, D_OUT, 0, stream>>>(y2, M, sum2, sq2);
    bnfactors<<<1, D_OUT, 0, stream>>>(sum2, sq2, g2, be2, f2, D_OUT, M);

    bnrelu_out<<<(M * D_OUT / 4 + 255) / 256, 256, 0, stream>>>(y2, f2, outp, M * D_OUT / 4);
}

// Round 7
// 398.624 us; speedup vs baseline: 4.2149x; 1.2506x over previous
//
#include <hip/hip_runtime.h>

#define D_IN 128
#define D_HID 256
#define D_OUT 128
#define BN_EPS 1e-5f

// ---------------------------------------------------------------------------
// 1) histogram: cnt[rows[e]]++  (int atomics on 200 KB — cheap)
// ---------------------------------------------------------------------------
__global__ __launch_bounds__(256) void edge_hist(
    const int* __restrict__ rows, int* __restrict__ cnt, int E)
{
    int e = blockIdx.x * 256 + threadIdx.x;
    if (e < E) atomicAdd(&cnt[rows[e]], 1);
}

// ---------------------------------------------------------------------------
// 2a) per-chunk sums: bsum[b] = sum of cnt[b*256 .. b*256+255]  (coalesced)
// ---------------------------------------------------------------------------
__global__ __launch_bounds__(256) void chunk_sums(
    const int* __restrict__ cnt, int* __restrict__ bsum, int N)
{
    __shared__ int red[256];
    const int t = threadIdx.x;
    const int i = blockIdx.x * 256 + t;
    red[t] = (i < N) ? cnt[i] : 0;
    __syncthreads();
#pragma unroll
    for (int off = 128; off > 0; off >>= 1) {
        if (t < off) red[t] += red[t + off];
        __syncthreads();
    }
    if (t == 0) bsum[blockIdx.x] = red[0];
}

// ---------------------------------------------------------------------------
// 2b) scan chunk sums (NB <= 256): coff[b] = exclusive prefix of bsum
// ---------------------------------------------------------------------------
__global__ __launch_bounds__(256) void scan_chunks(
    const int* __restrict__ bsum, int* __restrict__ coff, int NB)
{
    __shared__ int s[256];
    const int t = threadIdx.x;
    int c = (t < NB) ? bsum[t] : 0;
    s[t] = c;
    __syncthreads();
#pragma unroll
    for (int off = 1; off < 256; off <<= 1) {
        int x = (t >= off) ? s[t - off] : 0;
        __syncthreads();
        s[t] += x;
        __syncthreads();
    }
    coff[t] = s[t] - c;   // exclusive
}

// ---------------------------------------------------------------------------
// 2c) block-local scan + chunk offset -> rowstart[N+1], cursor[N]
// ---------------------------------------------------------------------------
__global__ __launch_bounds__(256) void scan_write(
    const int* __restrict__ cnt, const int* __restrict__ coff,
    int* __restrict__ rowstart, int* __restrict__ cursor, int N)
{
    __shared__ int s[256];
    const int t = threadIdx.x;
    const int i = blockIdx.x * 256 + t;
    int c = (i < N) ? cnt[i] : 0;
    s[t] = c;
    __syncthreads();
#pragma unroll
    for (int off = 1; off < 256; off <<= 1) {
        int x = (t >= off) ? s[t - off] : 0;
        __syncthreads();
        s[t] += x;
        __syncthreads();
    }
    int pos = coff[blockIdx.x] + s[t] - c;   // global exclusive prefix
    if (i < N) {
        rowstart[i] = pos;
        cursor[i] = pos;
    } else if (i == N) {
        rowstart[N] = pos;                   // == E
    }
}

// ---------------------------------------------------------------------------
// 3) scatter edges into row-bucketed order: ecv[pos] = (col, val)
// ---------------------------------------------------------------------------
__global__ __launch_bounds__(256) void edge_scatter(
    const int* __restrict__ rows, const int* __restrict__ cols,
    const float* __restrict__ vals, int* __restrict__ cursor,
    float2* __restrict__ ecv, int E)
{
    int e = blockIdx.x * 256 + threadIdx.x;
    if (e >= E) return;
    int r = rows[e];
    int pos = atomicAdd(&cursor[r], 1);
    ecv[pos] = make_float2(__int_as_float(cols[e]), vals[e]);
}

// ---------------------------------------------------------------------------
// 4) gather-aggregate: one wave per row, 2 edges in flight per iteration.
//    half = lane>>5 selects edge of the pair; 32 lanes × float4 = 128 feats.
//    Writes x[r] = sum_e val_e * v[col_e] + eps * v[r]  (no memset needed).
// ---------------------------------------------------------------------------
__global__ __launch_bounds__(256) void spmm_rows(
    const float* __restrict__ v, const int* __restrict__ rowstart,
    const float2* __restrict__ ecv, const float* __restrict__ epsp,
    float* __restrict__ x, int N)
{
    int wid = (blockIdx.x * 256 + threadIdx.x) >> 6;   // wave id == row
    if (wid >= N) return;
    const int lane = threadIdx.x & 63;
    const int half = lane >> 5;         // which edge of the pair
    const int l32 = lane & 31;          // feat group: 4 floats
    const int s = rowstart[wid], e = rowstart[wid + 1];
    float4 acc = make_float4(0.f, 0.f, 0.f, 0.f);

    for (int base = s; base < e; base += 64) {
        int n = min(64, e - base);
        // pad lanes get val=0, col=0 -> harmless v[0] read, adds 0
        float2 ev = make_float2(0.f, 0.f);
        if (base + lane < e) ev = ecv[base + lane];
        int mycol = __float_as_int(ev.x);
        int pairs = (n + 1) >> 1;
        for (int k = 0; k < pairs; ++k) {
            int idx = 2 * k + half;
            int col = __shfl(mycol, idx);
            float val = __shfl(ev.y, idx);
            const float4 vv = *reinterpret_cast<const float4*>(
                v + (size_t)col * D_IN + l32 * 4);
            acc.x = fmaf(val, vv.x, acc.x);
            acc.y = fmaf(val, vv.y, acc.y);
            acc.z = fmaf(val, vv.z, acc.z);
            acc.w = fmaf(val, vv.w, acc.w);
        }
    }
    // combine the two half-wave accumulators (same feats, different edges)
    acc.x += __shfl_down(acc.x, 32);
    acc.y += __shfl_down(acc.y, 32);
    acc.z += __shfl_down(acc.z, 32);
    acc.w += __shfl_down(acc.w, 32);
    if (half == 0) {
        const float eps = *epsp;
        const float4 vs = *reinterpret_cast<const float4*>(
            v + (size_t)wid * D_IN + l32 * 4);
        float4 o;
        o.x = fmaf(eps, vs.x, acc.x);
        o.y = fmaf(eps, vs.y, acc.y);
        o.z = fmaf(eps, vs.z, acc.z);
        o.w = fmaf(eps, vs.w, acc.w);
        *reinterpret_cast<float4*>(x + (size_t)wid * D_IN + l32 * 4) = o;
    }
}

// ---------------------------------------------------------------------------
// 5) GEMM1: y1 = x @ w1   [M,128]x[128,256] -> [M,256]
//    + fused column sum/sumsq epilogue (BN1 batch stats)
// ---------------------------------------------------------------------------
__global__ __launch_bounds__(256) void gemm1(
    const float* __restrict__ x, const float* __restrict__ w1,
    float* __restrict__ y1, float* __restrict__ sum, float* __restrict__ sq,
    int M)
{
    __shared__ __align__(16) float As[32][68];   // [k][m], padded
    __shared__ __align__(16) float Bs[32][64];   // [k][n]
    const int tid = threadIdx.x;
    const int bm = blockIdx.x * 64;
    const int bn = blockIdx.y * 64;
    const int lr = tid >> 3, lc = (tid & 7) << 2;
    const int br = tid >> 4, bc = (tid & 15) << 2;
    const int ty = tid >> 4, tx = tid & 15;
    float acc[4][4] = {};

    for (int kk = 0; kk < D_IN; kk += 32) {
#pragma unroll
        for (int h = 0; h < 2; ++h) {
            int row = bm + lr + h * 32;
            float4 a = make_float4(0.f, 0.f, 0.f, 0.f);
            if (row < M)
                a = *reinterpret_cast<const float4*>(x + (size_t)row * D_IN + kk + lc);
            As[lc + 0][lr + h * 32] = a.x;
            As[lc + 1][lr + h * 32] = a.y;
            As[lc + 2][lr + h * 32] = a.z;
            As[lc + 3][lr + h * 32] = a.w;
        }
#pragma unroll
        for (int h = 0; h < 2; ++h) {
            int krow = kk + br + h * 16;
            *reinterpret_cast<float4*>(&Bs[br + h * 16][bc]) =
                *reinterpret_cast<const float4*>(w1 + (size_t)krow * D_HID + bn + bc);
        }
        __syncthreads();
#pragma unroll
        for (int k = 0; k < 32; ++k) {
            float4 a4 = *reinterpret_cast<float4*>(&As[k][ty * 4]);
            float4 b4 = *reinterpret_cast<float4*>(&Bs[k][tx * 4]);
            float af[4] = {a4.x, a4.y, a4.z, a4.w};
            float bf[4] = {b4.x, b4.y, b4.z, b4.w};
#pragma unroll
            for (int i = 0; i < 4; ++i)
#pragma unroll
                for (int j = 0; j < 4; ++j)
                    acc[i][j] = fmaf(af[i], bf[j], acc[i][j]);
        }
        __syncthreads();
    }
#pragma unroll
    for (int i = 0; i < 4; ++i) {
        int row = bm + ty * 4 + i;
        if (row < M) {
            float4 o = make_float4(acc[i][0], acc[i][1], acc[i][2], acc[i][3]);
            *reinterpret_cast<float4*>(y1 + (size_t)row * D_HID + bn + tx * 4) = o;
        }
    }
    // --- fused column-stats epilogue (rows >= M contribute exactly 0) ---
    float* red = &As[0][0];   // reuse: 2048 floats needed, As has 2176
#pragma unroll
    for (int j = 0; j < 4; ++j) {
        float s = acc[0][j] + acc[1][j] + acc[2][j] + acc[3][j];
        float q = acc[0][j] * acc[0][j] + acc[1][j] * acc[1][j]
                + acc[2][j] * acc[2][j] + acc[3][j] * acc[3][j];
        red[ty * 64 + tx * 4 + j]        = s;
        red[1024 + ty * 64 + tx * 4 + j] = q;
    }
    __syncthreads();
    if (tid < 64) {
        float s = 0.f, q = 0.f;
#pragma unroll
        for (int t = 0; t < 16; ++t) {
            s += red[t * 64 + tid];
            q += red[1024 + t * 64 + tid];
        }
        atomicAdd(&sum[bn + tid], s);
        atomicAdd(&sq[bn + tid], q);
    }
}

// ---------------------------------------------------------------------------
// 6) GEMM2: y2 = relu(y1*s1+t1) @ w2   (BN1+ReLU fused into A staging)
//    + fused column sum/sumsq epilogue (BN2 batch stats)
// ---------------------------------------------------------------------------
__global__ __launch_bounds__(256) void gemm2(
    const float* __restrict__ y1, const float2* __restrict__ f1,
    const float* __restrict__ w2, float* __restrict__ y2,
    float* __restrict__ sum, float* __restrict__ sq, int M)
{
    __shared__ __align__(16) float As[32][68];
    __shared__ __align__(16) float Bs[32][64];
    const int tid = threadIdx.x;
    const int bm = blockIdx.x * 64;
    const int bn = blockIdx.y * 64;
    const int lr = tid >> 3, lc = (tid & 7) << 2;
    const int br = tid >> 4, bc = (tid & 15) << 2;
    const int ty = tid >> 4, tx = tid & 15;
    float acc[4][4] = {};

    for (int kk = 0; kk < D_HID; kk += 32) {
#pragma unroll
        for (int h = 0; h < 2; ++h) {
            int row = bm + lr + h * 32;
            float4 a = make_float4(0.f, 0.f, 0.f, 0.f);
            if (row < M) {
                const float4 xx = *reinterpret_cast<const float4*>(y1 + (size_t)row * D_HID + kk + lc);
                float2 fa = f1[kk + lc + 0];
                float2 fb = f1[kk + lc + 1];
                float2 fc = f1[kk + lc + 2];
                float2 fd = f1[kk + lc + 3];
                a.x = fmaxf(fmaf(xx.x, fa.x, fa.y), 0.f);
                a.y = fmaxf(fmaf(xx.y, fb.x, fb.y), 0.f);
                a.z = fmaxf(fmaf(xx.z, fc.x, fc.y), 0.f);
                a.w = fmaxf(fmaf(xx.w, fd.x, fd.y), 0.f);
            }
            As[lc + 0][lr + h * 32] = a.x;
            As[lc + 1][lr + h * 32] = a.y;
            As[lc + 2][lr + h * 32] = a.z;
            As[lc + 3][lr + h * 32] = a.w;
        }
#pragma unroll
        for (int h = 0; h < 2; ++h) {
            int krow = kk + br + h * 16;
            *reinterpret_cast<float4*>(&Bs[br + h * 16][bc]) =
                *reinterpret_cast<const float4*>(w2 + (size_t)krow * D_OUT + bn + bc);
        }
        __syncthreads();
#pragma unroll
        for (int k = 0; k < 32; ++k) {
            float4 a4 = *reinterpret_cast<float4*>(&As[k][ty * 4]);
            float4 b4 = *reinterpret_cast<float4*>(&Bs[k][tx * 4]);
            float af[4] = {a4.x, a4.y, a4.z, a4.w};
            float bf[4] = {b4.x, b4.y, b4.z, b4.w};
#pragma unroll
            for (int i = 0; i < 4; ++i)
#pragma unroll
                for (int j = 0; j < 4; ++j)
                    acc[i][j] = fmaf(af[i], bf[j], acc[i][j]);
        }
        __syncthreads();
    }
#pragma unroll
    for (int i = 0; i < 4; ++i) {
        int row = bm + ty * 4 + i;
        if (row < M) {
            float4 o = make_float4(acc[i][0], acc[i][1], acc[i][2], acc[i][3]);
            *reinterpret_cast<float4*>(y2 + (size_t)row * D_OUT + bn + tx * 4) = o;
        }
    }
    // --- fused column-stats epilogue ---
    float* red = &As[0][0];
#pragma unroll
    for (int j = 0; j < 4; ++j) {
        float s = acc[0][j] + acc[1][j] + acc[2][j] + acc[3][j];
        float q = acc[0][j] * acc[0][j] + acc[1][j] * acc[1][j]
                + acc[2][j] * acc[2][j] + acc[3][j] * acc[3][j];
        red[ty * 64 + tx * 4 + j]        = s;
        red[1024 + ty * 64 + tx * 4 + j] = q;
    }
    __syncthreads();
    if (tid < 64) {
        float s = 0.f, q = 0.f;
#pragma unroll
        for (int t = 0; t < 16; ++t) {
            s += red[t * 64 + tid];
            q += red[1024 + t * 64 + tid];
        }
        atomicAdd(&sum[bn + tid], s);
        atomicAdd(&sq[bn + tid], q);
    }
}

// ---------------------------------------------------------------------------
// 7) BN factors: s = g*rsqrt(var+eps); t = be - mean*s   (bias cancels in BN)
// ---------------------------------------------------------------------------
__global__ void bnfactors(const float* __restrict__ sum, const float* __restrict__ sq,
                          const float* __restrict__ g, const float* __restrict__ be,
                          float2* __restrict__ f, int C, int M)
{
    int c = threadIdx.x;
    if (c < C) {
        float inv = 1.f / (float)M;
        float mean = sum[c] * inv;
        float var = fmaxf(sq[c] * inv - mean * mean, 0.f);
        float s = g[c] * rsqrtf(var + BN_EPS);
        f[c] = make_float2(s, be[c] - mean * s);
    }
}

// ---------------------------------------------------------------------------
// 8) final elementwise: out = relu(y2*s2 + t2)
// ---------------------------------------------------------------------------
__global__ __launch_bounds__(256) void bnrelu_out(
    const float* __restrict__ y2, const float2* __restrict__ f2,
    float* __restrict__ out, int total4)
{
    int i = blockIdx.x * 256 + threadIdx.x;
    if (i >= total4) return;
    float4 x = reinterpret_cast<const float4*>(y2)[i];
    int c = (i & (D_OUT / 4 - 1)) << 2;
    float2 fa = f2[c + 0];
    float2 fb = f2[c + 1];
    float2 fc = f2[c + 2];
    float2 fd = f2[c + 3];
    float4 o;
    o.x = fmaxf(fmaf(x.x, fa.x, fa.y), 0.f);
    o.y = fmaxf(fmaf(x.y, fb.x, fb.y), 0.f);
    o.z = fmaxf(fmaf(x.z, fc.x, fc.y), 0.f);
    o.w = fmaxf(fmaf(x.w, fd.x, fd.y), 0.f);
    reinterpret_cast<float4*>(out)[i] = o;
}

// ---------------------------------------------------------------------------
extern "C" void kernel_launch(void* const* d_in, const int* in_sizes, int n_in,
                              void* d_out, int out_size, void* d_ws, size_t ws_size,
                              hipStream_t stream)
{
    const float* v     = (const float*)d_in[0];
    const int*   erows = (const int*)d_in[1];
    const int*   ecols = (const int*)d_in[2];
    const float* evals = (const float*)d_in[3];
    const float* w1    = (const float*)d_in[4];
    // b1 = d_in[5], b2 = d_in[9]: linear bias cancels exactly inside BatchNorm.
    const float* g1    = (const float*)d_in[6];
    const float* be1   = (const float*)d_in[7];
    const float* w2    = (const float*)d_in[8];
    const float* g2    = (const float*)d_in[10];
    const float* be2   = (const float*)d_in[11];
    const float* eps   = (const float*)d_in[12];

    const int M = in_sizes[0] / D_IN;   // 50000
    const int E = in_sizes[3];          // 800000
    const int NB = (M + 255) / 256;     // 196 chunks (NB <= 256 required)

    float* ws   = (float*)d_ws;
    float* x    = ws;                               // M*128  (agg + eps*v)
    float* y1   = x + (size_t)M * D_IN;             // M*256
    int*  rowstart = (int*)(y1 + (size_t)M * D_HID); // N+1
    int*  cursor   = rowstart + M + 2;              // N (pad keeps 8B align)
    int*  cnthist  = cursor + M;                    // N counts
    int*  bsum     = cnthist + M;                   // 256 chunk sums
    int*  coff     = bsum + 256;                    // 256 chunk offsets
    size_t ecv_ofs = ((size_t)(coff + 256 - (int*)ws) + 1) & ~(size_t)1;
    float2* ecv = (float2*)((float*)ws + ecv_ofs);  // E float2
    float* st   = (float*)(ecv + E);
    float* sum1 = st;
    float* sq1  = sum1 + D_HID;
    float* sum2 = sq1 + D_HID;
    float* sq2  = sum2 + D_OUT;
    float2* f1  = (float2*)(sq2 + D_OUT);           // 256 float2
    float2* f2  = f1 + D_HID;                       // 128 float2
    float* y2   = x;                                // alias: x dead after GEMM1
    float* outp = (float*)d_out;

    hipMemsetAsync(cnthist, 0, (size_t)M * sizeof(int), stream);
    hipMemsetAsync(st, 0, (size_t)(2 * D_HID + 2 * D_OUT) * sizeof(float), stream);

    edge_hist<<<(E + 255) / 256, 256, 0, stream>>>(erows, cnthist, E);
    chunk_sums<<<NB, 256, 0, stream>>>(cnthist, bsum, M);
    scan_chunks<<<1, 256, 0, stream>>>(bsum, coff, NB);
    scan_write<<<NB, 256, 0, stream>>>(cnthist, coff, rowstart, cursor, M);
    edge_scatter<<<(E + 255) / 256, 256, 0, stream>>>(erows, ecols, evals, cursor, ecv, E);
    spmm_rows<<<(M * 64 + 255) / 256, 256, 0, stream>>>(v, rowstart, ecv, eps, x, M);

    dim3 grid1((M + 63) / 64, D_HID / 64);
    gemm1<<<grid1, 256, 0, stream>>>(x, w1, y1, sum1, sq1, M);
    bnfactors<<<1, D_HID, 0, stream>>>(sum1, sq1, g1, be1, f1, D_HID, M);

    dim3 grid2((M + 63) / 64, D_OUT / 64);
    gemm2<<<grid2, 256, 0, stream>>>(y1, f1, w2, y2, sum2, sq2, M);
    bnfactors<<<1, D_OUT, 0, stream>>>(sum2, sq2, g2, be2, f2, D_OUT, M);

    bnrelu_out<<<(M * D_OUT / 4 + 255) / 256, 256, 0, stream>>>(y2, f2, outp, M * D_OUT / 4);
}